// Round 9
// baseline (59.382 us; speedup 1.0000x reference)
//
#include <hip/hip_runtime.h>
#include <hip/hip_bf16.h>

#define NCLS 13
#define ROWS 16                          // rows per tile
#define BLOCK 256                        // 4 waves; wave w owns rows 4w..4w+3
#define TPB 16                           // tiles per block
#define NBUF 4                           // quad buffer, 3-deep prefetch
#define C_FLOATS (ROWS * NCLS * NCLS)    // 2704 floats (10816 B)
#define XS_FLOATS (ROWS * NCLS)          // 208 floats
#define CW 676                           // C floats per wave (4 rows * 169)
#define CW4 169                          // C float4s per wave

// async global->LDS DMA, 16B/lane; HW writes LDS at uniform base + lane*16
__device__ __forceinline__ void async_cp16(const float* g, float* l) {
    __builtin_amdgcn_global_load_lds(
        (__attribute__((address_space(1))) void*)(const_cast<float*>(g)),
        (__attribute__((address_space(3))) void*)(l),
        16, 0, 0);
}

__global__ __launch_bounds__(BLOCK) void rnorm_kernel(
    const float* __restrict__ input,
    const int* __restrict__ target,
    const float* __restrict__ s,
    const float* __restrict__ C,
    float* __restrict__ out,
    int ntiles)
{
    // 4 * (10816 + 832 + 832 + 64) = 50176 B -> 3 blocks/CU
    __shared__ __align__(16) float cb[NBUF][C_FLOATS];
    __shared__ __align__(16) float xb[NBUF][XS_FLOATS];
    __shared__ __align__(16) float sb[NBUF][XS_FLOATS];
    __shared__ __align__(16) int   tb[NBUF][ROWS];
    __shared__ float wsum[4];

    const int tid  = threadIdx.x;
    const int w    = tid >> 6;    // wave 0..3
    const int lane = tid & 63;
    const int row  = tid >> 4;    // 0..15
    const int q    = tid & 15;    // 16 lanes per row, 13 active

    const int tile0 = blockIdx.x * TPB;
    const int nt = min(TPB, ntiles - tile0);
    float res_acc = 0.0f;

    // Exactly 4 global_load_lds per wave per stage (per-wave vmcnt accounting).
    // All C addressing in float4 units.
    auto stage = [&](int t_idx, int buf) {
        const int tile = tile0 + t_idx;
        const float4* Cg = (const float4*)(C + (size_t)tile * C_FLOATS) + w * CW4;
        float* cd = &cb[buf][w * CW];
        async_cp16((const float*)(Cg + lane),       cd + (size_t)lane * 4);
        async_cp16((const float*)(Cg + 64 + lane),  cd + (size_t)(64 + lane) * 4);
        if (lane < CW4 - 128)
            async_cp16((const float*)(Cg + 128 + lane), cd + (size_t)(128 + lane) * 4);
        if (w == 0) {
            const float4* xg = (const float4*)(input + (size_t)tile * XS_FLOATS);
            if (lane < XS_FLOATS / 4)
                async_cp16((const float*)(xg + lane), &xb[buf][0] + (size_t)lane * 4);
        } else if (w == 1) {
            const float4* sg = (const float4*)(s + (size_t)tile * XS_FLOATS);
            if (lane < XS_FLOATS / 4)
                async_cp16((const float*)(sg + lane), &sb[buf][0] + (size_t)lane * 4);
        } else {  // waves 2 and 3 both stage targets (identical data, benign)
            if (lane < ROWS / 4)
                async_cp16((const float*)(target + (size_t)tile * ROWS) + (size_t)lane * 4,
                           (float*)&tb[buf][0] + (size_t)lane * 4);
        }
    };

    if (nt > 0) {
        // prologue: 3-deep prefetch
        stage(0, 0);
        if (nt > 1) stage(1, 1);
        if (nt > 2) stage(2, 2);
        if (nt > 2)      asm volatile("s_waitcnt vmcnt(8)" ::: "memory");
        else if (nt > 1) asm volatile("s_waitcnt vmcnt(4)" ::: "memory");
        else             asm volatile("s_waitcnt vmcnt(0)" ::: "memory");
        __builtin_amdgcn_sched_barrier(0);
        __builtin_amdgcn_s_barrier();

        int bcur = 0;
        for (int t = 0; t < nt; ++t) {
            // issue tile t+3 (two stages stay in flight across the barrier)
            if (t + 3 < nt) {
                int bpre = bcur + 3; if (bpre >= NBUF) bpre -= NBUF;
                stage(t + 3, bpre);
            }

            // ---- compute tile t from LDS ----
            const float* cbt = cb[bcur];
            const float* xbt = xb[bcur];
            const float* sbt = sb[bcur];
            const int tt = tb[bcur][row];

            float sp = 0.0f, sy = 0.0f, dd = 0.0f;
            if (q < NCLS) {
                const float* crow = cbt + row * (NCLS * NCLS) + q * NCLS;
                const float* xrow = xbt + row * NCLS;
                float zye = 0.0f;
#pragma unroll
                for (int j = 0; j < NCLS; ++j)
                    zye = fmaf(crow[j], xrow[j], zye);
                const float zpe = crow[tt];            // one-hot column
                const float svi = sbt[row * NCLS + q];
                const float zp = svi - zpe, zy = svi - zye;
                sp = zp * zp; sy = zy * zy; dd = zy * zp;
            }

            sp += __shfl_xor(sp, 1); sp += __shfl_xor(sp, 2);
            sp += __shfl_xor(sp, 4); sp += __shfl_xor(sp, 8);
            sy += __shfl_xor(sy, 1); sy += __shfl_xor(sy, 2);
            sy += __shfl_xor(sy, 4); sy += __shfl_xor(sy, 8);
            dd += __shfl_xor(dd, 1); dd += __shfl_xor(dd, 2);
            dd += __shfl_xor(dd, 4); dd += __shfl_xor(dd, 8);

            if (q == 0)
                res_acc += sqrtf(sp) - dd / sqrtf(sy);

            if (t + 1 < nt) {
                // counted wait: tile t+1 landed; t+2/t+3 stay in flight
                if (t + 3 < nt)      asm volatile("s_waitcnt vmcnt(8)" ::: "memory");
                else if (t + 2 < nt) asm volatile("s_waitcnt vmcnt(4)" ::: "memory");
                else                 asm volatile("s_waitcnt vmcnt(0)" ::: "memory");
                __builtin_amdgcn_sched_barrier(0);
                __builtin_amdgcn_s_barrier();   // raw barrier: no implicit drain
            }
            bcur = (bcur + 1 == NBUF) ? 0 : bcur + 1;
        }
    }

    // ---- block reduction ----
#pragma unroll
    for (int off = 32; off > 0; off >>= 1)
        res_acc += __shfl_down(res_acc, off, 64);

    if (lane == 0) wsum[w] = res_acc;
    __syncthreads();
    if (tid == 0)
        atomicAdd(out, wsum[0] + wsum[1] + wsum[2] + wsum[3]);
}

extern "C" void kernel_launch(void* const* d_in, const int* in_sizes, int n_in,
                              void* d_out, int out_size, void* d_ws, size_t ws_size,
                              hipStream_t stream) {
    const float* input  = (const float*)d_in[0];
    const int*   target = (const int*)d_in[1];   // harness passes integers as int32
    const float* s      = (const float*)d_in[2];
    const float* C      = (const float*)d_in[3];
    // d_in[4] (instance_weights) is unused by the reference.

    float* out = (float*)d_out;
    int N = in_sizes[1];

    // harness poisons d_out and does not re-zero between replays
    hipMemsetAsync(out, 0, sizeof(float) * out_size, stream);

    const int ntiles = N / ROWS;                 // 16384
    const int grid = (ntiles + TPB - 1) / TPB;   // 1024
    rnorm_kernel<<<grid, BLOCK, 0, stream>>>(input, target, s, C, out, ntiles);
}